// Round 12
// baseline (173.031 us; speedup 1.0000x reference)
//
#include <hip/hip_runtime.h>

#define C_ 512
#define L_ 784
#define K_ 64
#define EPS_ 1e-12f
#define SLS 264   // sl row stride in floats: 264 % 32 == 8 -> q-groups hit
                  // distinct bank sets (256 == 0 mod 32 was an 8-way conflict)

typedef _Float16 half_t;
typedef _Float16 half4 __attribute__((ext_vector_type(4)));
typedef float float4v __attribute__((ext_vector_type(4)));

// ---------------------------------------------------------------------------
// kF v10 = v9 (1 barrier/subtile, lagged agg) with the agg fragments kept in
// REGISTERS (bhp[8]) instead of re-read from LDS: -8 ds_read_b64 per
// wave-subtile (the largest remaining DS-pipe slice after r11's fixes).
// The v5/v6 spill failure is avoided by __launch_bounds__(1024, 4): LDS
// (102 KB) pins 1 block/CU anyway, so declaring 4 waves/EU grants the true
// 128-reg budget of the unified VGPR/AGPR file.  Live set ~114 < 128
// (agc 32 + bhp 16 + bnc 16 + wf 16 + g 8 + lc 8 + misc).
// lc reduced 4 -> 2 accumulators for register headroom (4-deep MFMA chain,
// hidden by 4 waves/SIMD).
// grid (4, 64), block 1024 (16 waves = 4 kt x 4 cs).
// Per 16-l subtile s (ONE barrier):
//   0. g0,g1 = dwordx4 loads of subtile s+2 (transient; sched_barrier pin)
//   1. logits(s): bnc[i] = ds_read xs[s&3]; T = mfma(bnc,I); lc += mfma(T,wf)
//   2. sl[s&1] partials (xlog2e, padded stride); BARRIER
//   3. softmax(s): wave=l-row, lane=k, shfl_xor trees, exp2; ah[s&1]; asum
//   4. cvt g -> ds_write xs[(s+2)&3]
//   5. lagged agg(s-1): agc[i] += mfma(ah[(s-1)&1], bhp[i])  (regs, no LDS)
//   6. bhp = bnc
// Buffer skew (all LDS write/read pairs >=1 barrier apart): xs 4-deep
// (write s+2 window s, read window s+2), sl/ah 2-deep.
// MFMA maps verified end-to-end r3-r11 (passed, absmax 1.2e-4):
//   A: m=lane&15, kk=q*4+j; B: n=lane&15, kk=q*4+j; D: row=q*4+r, col=lane&15.
// ---------------------------------------------------------------------------
__global__ __launch_bounds__(1024, 4) void kF(const float* __restrict__ x,
                                              const float* __restrict__ w,
                                              float* __restrict__ aggP,
                                              float* __restrict__ asumP) {
    __shared__ half_t xs[4][32 * 256];    // 64 KB: [buf][tile = cs*8+i][slot*4] fp16
    __shared__ float  sl[2][16 * SLS];    // 33 KB: [buf][l][k*4+cs] padded partials
    __shared__ half_t ah[2][64 * 20];     //  5 KB: [buf][k][16 l + pad]

    const int t    = threadIdx.x;
    const int n    = blockIdx.y;
    const int bx   = blockIdx.x;
    const int l0   = bx * 192;
    const int NT   = (bx == 3) ? 13 : 12;   // 3*192 + 208 = 784
    const int wv   = t >> 6;
    const int lane = t & 63;
    const int m16  = lane & 15;
    const int q    = lane >> 4;
    const int kt   = wv & 3;   // k-tile (16 k)
    const int cs   = wv >> 2;  // c-segment (128 c = 8 tiles of 16)

    const float* xn = x + (size_t)n * (C_ * L_);

    // staging: wave wv owns tiles T0 = 2wv, T0+1 (tile T: cs = T>>3, i = T&7)
    const int T0 = 2 * wv;
    const float* src0 = xn + (size_t)((T0 >> 3) * 128 + (T0 & 7) * 16 + m16) * L_ + l0 + 4 * q;
    const float* src1 = xn + (size_t)(((T0 + 1) >> 3) * 128 + ((T0 + 1) & 7) * 16 + m16) * L_ + l0 + 4 * q;

    // prologue: stage subtiles 0 and 1
#pragma unroll
    for (int s0 = 0; s0 < 2; ++s0) {
        float4v g0 = *(const float4v*)(src0 + 16 * s0);
        float4v g1 = *(const float4v*)(src1 + 16 * s0);
        *(half4*)&xs[s0][T0 * 256 + lane * 4] =
            half4{(half_t)g0[0], (half_t)g0[1], (half_t)g0[2], (half_t)g0[3]};
        *(half4*)&xs[s0][(T0 + 1) * 256 + lane * 4] =
            half4{(half_t)g1[0], (half_t)g1[1], (half_t)g1[2], (half_t)g1[3]};
    }

    // w fragments (B-style): lane m16 -> k row, elems j -> c = cs*128+i*16+4q+j
    half4 wf[8];
#pragma unroll
    for (int i = 0; i < 8; ++i) {
        float4v f = *(const float4v*)(w + (size_t)(kt * 16 + m16) * C_ +
                                      cs * 128 + i * 16 + 4 * q);
        wf[i] = half4{(half_t)f[0], (half_t)f[1], (half_t)f[2], (half_t)f[3]};
    }
    // identity B-fragment: I[kk=4q+j][n=m16]
    half4 ifr;
#pragma unroll
    for (int j = 0; j < 4; ++j) ifr[j] = (half_t)((4 * q + j == m16) ? 1.0f : 0.0f);

    const float4v z4 = {0.f, 0.f, 0.f, 0.f};
    const float LOG2E = 1.4426950408889634f;
    float4v agc[8];
#pragma unroll
    for (int i = 0; i < 8; ++i) agc[i] = z4;
    half4 bhp[8];              // previous subtile's x fragments (agg B-operands)
    float asum_reg = 0.f;

    __syncthreads();

    for (int s = 0; s < NT; ++s) {
        // 0. transient prefetch of subtile s+2 (written to LDS at step 4)
        float4v g0, g1;
        const bool pf = (s + 2 < NT);
        if (pf) {
            g0 = *(const float4v*)(src0 + 16 * (s + 2));
            g1 = *(const float4v*)(src1 + 16 * (s + 2));
        }
        __builtin_amdgcn_sched_barrier(0);   // pin load issue at loop top
        // 1. logits(s) from xs[s&3]; fragments kept in bnc for the lagged agg
        const half_t* xb = &xs[s & 3][(cs * 8) * 256];
        half4 bnc[8];
        float4v lc0 = z4, lc1 = z4;
#pragma unroll
        for (int i = 0; i < 8; ++i) {
            bnc[i] = *(const half4*)&xb[i * 256 + lane * 4];
            float4v xt = __builtin_amdgcn_mfma_f32_16x16x16f16(bnc[i], ifr, z4, 0, 0, 0);
            half4 a4 = {(half_t)xt[0], (half_t)xt[1], (half_t)xt[2], (half_t)xt[3]};
            if (i & 1) lc1 = __builtin_amdgcn_mfma_f32_16x16x16f16(a4, wf[i], lc1, 0, 0, 0);
            else       lc0 = __builtin_amdgcn_mfma_f32_16x16x16f16(a4, wf[i], lc0, 0, 0, 0);
        }
        float4v lac = lc0 + lc1;
        // 2. D[l][k] partials in log2 domain: row 4q+r = l_local, col m16 = k
        float* slb = sl[s & 1];
#pragma unroll
        for (int r = 0; r < 4; ++r)
            slb[(4 * q + r) * SLS + (kt * 16 + m16) * 4 + cs] = lac[r] * LOG2E;
        __syncthreads();   // the ONLY barrier per subtile
        // 3. softmax(s): wave wv = l-row, lane = k (log2-domain: exp2)
        {
            float4v p4 = *(const float4v*)&slb[wv * SLS + lane * 4];
            float lg = p4[0] + p4[1] + p4[2] + p4[3];
            float mx = lg;
#pragma unroll
            for (int off = 32; off; off >>= 1) mx = fmaxf(mx, __shfl_xor(mx, off, 64));
            float e = exp2f(lg - mx);
            float sm = e;
#pragma unroll
            for (int off = 32; off; off >>= 1) sm += __shfl_xor(sm, off, 64);
            float a = e / sm;
            asum_reg += a;
            ah[s & 1][lane * 20 + wv] = (half_t)a;
        }
        // 4. write staged subtile s+2 (readers: logits(s+2), after barrier(s+1))
        if (pf) {
            *(half4*)&xs[(s + 2) & 3][T0 * 256 + lane * 4] =
                half4{(half_t)g0[0], (half_t)g0[1], (half_t)g0[2], (half_t)g0[3]};
            *(half4*)&xs[(s + 2) & 3][(T0 + 1) * 256 + lane * 4] =
                half4{(half_t)g1[0], (half_t)g1[1], (half_t)g1[2], (half_t)g1[3]};
        }
        // 5. lagged agg(s-1): ah[(s-1)&1] complete (softmax(s-1) preceded
        //    barrier(s)); x fragments straight from bhp registers.
        if (s > 0) {
            half4 aA = *(const half4*)&ah[(s - 1) & 1][(kt * 16 + m16) * 20 + 4 * q];
#pragma unroll
            for (int i = 0; i < 8; ++i)
                agc[i] = __builtin_amdgcn_mfma_f32_16x16x16f16(aA, bhp[i], agc[i], 0, 0, 0);
        }
        // 6. roll fragments
#pragma unroll
        for (int i = 0; i < 8; ++i) bhp[i] = bnc[i];
    }

    // tail: final subtile's agg (barrier so ah[(NT-1)&1] is visible)
    __syncthreads();
    {
        half4 aA = *(const half4*)&ah[(NT - 1) & 1][(kt * 16 + m16) * 20 + 4 * q];
#pragma unroll
        for (int i = 0; i < 8; ++i)
            agc[i] = __builtin_amdgcn_mfma_f32_16x16x16f16(aA, bhp[i], agc[i], 0, 0, 0);
    }

    // ---- epilogue: asum reduce + direct coalesced agg stores ----
    // sl[0]'s last reader was softmax(NT-1) or earlier, all pre-tail-barrier.
    float* red = sl[0];
    red[wv * 64 + lane] = asum_reg;
    __syncthreads();
    if (t < 64) {
        float s_ = 0.f;
#pragma unroll
        for (int j = 0; j < 16; ++j) s_ += red[j * 64 + t];
        asumP[((size_t)n * 4 + bx) * 64 + t] = s_;
    }
    float* ap = aggP + (((size_t)n * 4 + bx) * 64) * (size_t)C_;
#pragma unroll
    for (int i = 0; i < 8; ++i)
#pragma unroll
        for (int r = 0; r < 4; ++r)
            ap[(size_t)(kt * 16 + 4 * q + r) * C_ + (cs * 8 + i) * 16 + m16] = agc[i][r];
}

// ---------------------------------------------------------------------------
// kC: reduce 4 agg partials, vlad = agg - asum*cent, intra-normalize per
// (n,k) over C; global norm is exactly 8.  grid (16,64) = 1024 blocks,
// 256 thr, ONE k-row per wave.  float4 loads/stores.
// ---------------------------------------------------------------------------
__global__ __launch_bounds__(256) void kC(const float* __restrict__ aggP,
                                          const float* __restrict__ cent,
                                          const float* __restrict__ asumP,
                                          float* __restrict__ out) {
    __shared__ float asumS[4];
    const int t  = threadIdx.x;
    const int n  = blockIdx.y;
    const int k0 = blockIdx.x * 4;
    if (t < 4) {
        float s = 0.f;
        for (int j = 0; j < 4; ++j) s += asumP[((size_t)n * 4 + j) * 64 + k0 + t];
        asumS[t] = s;
    }
    __syncthreads();
    const int wv   = t >> 6;
    const int lane = t & 63;
    const int k    = k0 + wv;
    const float as = asumS[wv];
    const float* a0 = aggP + (((size_t)n * 4 + 0) * 64 + k) * C_;
    const float* a1 = aggP + (((size_t)n * 4 + 1) * 64 + k) * C_;
    const float* a2 = aggP + (((size_t)n * 4 + 2) * 64 + k) * C_;
    const float* a3 = aggP + (((size_t)n * 4 + 3) * 64 + k) * C_;
    const float* cp = cent + (size_t)k * C_;
    float4v v[2];
    float ss = 0.f;
#pragma unroll
    for (int j = 0; j < 2; ++j) {
        const int c = 4 * lane + 256 * j;
        float4v val = *(const float4v*)(a0 + c);
        val = val + *(const float4v*)(a1 + c);
        val = val + *(const float4v*)(a2 + c);
        val = val + *(const float4v*)(a3 + c);
        float4v c4 = *(const float4v*)(cp + c);
#pragma unroll
        for (int e = 0; e < 4; ++e) {
            val[e] -= as * c4[e];
            ss += val[e] * val[e];
        }
        v[j] = val;
    }
#pragma unroll
    for (int off = 32; off; off >>= 1) ss += __shfl_xor(ss, off, 64);
    const float scale = 1.f / (fmaxf(sqrtf(ss), EPS_) * 8.f);
    float* op = out + (size_t)n * (K_ * C_) + (size_t)k * C_;
#pragma unroll
    for (int j = 0; j < 2; ++j) {
        float4v o = v[j];
#pragma unroll
        for (int e = 0; e < 4; ++e) o[e] *= scale;
        *(float4v*)(op + 4 * lane + 256 * j) = o;
    }
}

extern "C" void kernel_launch(void* const* d_in, const int* in_sizes, int n_in,
                              void* d_out, int out_size, void* d_ws, size_t ws_size,
                              hipStream_t stream) {
    (void)in_sizes; (void)n_in; (void)out_size; (void)ws_size;
    const float* x    = (const float*)d_in[0];   // (64, 512, 28, 28) fp32
    const float* w    = (const float*)d_in[1];   // (64, 512) fp32
    const float* cent = (const float*)d_in[2];   // (64, 512) fp32
    float* out = (float*)d_out;                  // (64, 32768) fp32

    // ws: aggP f32 [64 n][4 bx][64 k][512 c] = 33.6 MB ; asumP f32 [64][4][64]
    // = 64 KB.  Total 33.7 MB.
    char* base = (char*)d_ws;
    float* aggP  = (float*)base;
    float* asumP = aggP + (size_t)64 * 4 * 64 * 512;

    kF<<<dim3(4, 64), 1024, 0, stream>>>(x, w, aggP, asumP);
    kC<<<dim3(16, 64), 256, 0, stream>>>(aggP, cent, asumP, out);
}